// Round 14
// baseline (990.762 us; speedup 1.0000x reference)
//
#include <hip/hip_runtime.h>
#include <cmath>

#define HH 512
#define WW 512
#define NB 8
#define CIN 4
#define C2 32
#define C3 16
#define CF 8
#define HW (HH*WW)      /* 262144 */
#define NPIX (NB*HW)    /* 2097152 */
#define NBC 2           /* batches per conv chunk (ws_size < 267 MB) */

#define SEGC 10                          /* staged cols per thread (320/32) */
#define SW   320                         /* staged cols (304 used, P=24 halo) */
#define SVW  ((SW + (SW>>3) + 4) | 1)    /* float2 LDS row stride (swz3 pad) */
#define RSW  (256 + 32 + 4)

__device__ __forceinline__ float lrelu_f(float v){ return v < 0.f ? 0.2f*v : v; }
__device__ __forceinline__ int reflect_i(int i){ int r = i < 0 ? -i : i; return r >= HH ? 2*HH - 2 - r : r; }
__device__ __forceinline__ int swz(int j){ return j + (j >> 3); }

// ---------------------------------------------------------------------------
// Conv 3x3 (zero pad=1, OIHW). Thread = 2 rows x 4 cols x 8 oc. Weights
// transposed in LDS [g][ci][tap*8+oc]. UNR = ci-loop unroll factor:
//   conv2: UNR=4 -- grid-capped at 2 blk/CU (2 waves/SIMD) so VGPR up to
//          ~256 is free; 4 ci-iterations of loads in flight hide L2 latency.
//   conv1: UNR=2, conv3: UNR=1 -- these run 4 blk/CU, must stay <=128 VGPR.
// ---------------------------------------------------------------------------
#define CIBODY \
    { \
        const float* inc = inb + (size_t)ci*HW; \
        float v[4][6]; \
        _Pragma("unroll") \
        for (int dy=0;dy<4;dy++){ \
            const float* rowp = inc + hcofs[dy]; \
            float4 mq = *(const float4*)(rowp + col); \
            float v0 = (col > 0)    ? rowp[col-1] : 0.f; \
            float v5 = (col+4 < WW) ? rowp[col+4] : 0.f; \
            if (!hok[dy]){ mq.x=0.f; mq.y=0.f; mq.z=0.f; mq.w=0.f; v0=0.f; v5=0.f; } \
            v[dy][0]=v0; v[dy][1]=mq.x; v[dy][2]=mq.y; \
            v[dy][3]=mq.z; v[dy][4]=mq.w; v[dy][5]=v5; \
        } \
        const float* wp = &wl[(cg*Ci + ci)*72]; \
        _Pragma("unroll") \
        for (int t=0;t<9;t++){ \
            int dy = t/3, dx = t - 3*(t/3); \
            float w8[8]; \
            _Pragma("unroll") \
            for (int o=0;o<8;o++) w8[o] = wp[t*8 + o]; \
            _Pragma("unroll") \
            for (int o=0;o<8;o++) \
                _Pragma("unroll") \
                for (int r=0;r<2;r++) \
                    _Pragma("unroll") \
                    for (int p=0;p<4;p++) \
                        acc[o][r][p] = fmaf(v[dy+r][dx+p], w8[o], acc[o][r][p]); \
        } \
    }

template<int Ci, int Co, bool LRELU, int UNR>
__global__ __launch_bounds__(256) void k_conv8(const float* __restrict__ in,
                                               const float* __restrict__ wgt,
                                               const float* __restrict__ bias,
                                               float* __restrict__ outp)
{
    constexpr int NG = Co/8;
    __shared__ float wl[NG*Ci*72];   // [g][ci][tap*8+ocl]
    __shared__ float bl[Co];
    for (int i = threadIdx.x; i < Co*Ci*9; i += 256){
        int g  = i / (Ci*72);
        int r  = i - g*(Ci*72);
        int ci = r / 72;
        int q  = r - ci*72;
        int tap = q >> 3, ocl = q & 7;
        wl[i] = wgt[((g*8 + ocl)*Ci + ci)*9 + tap];
    }
    if (threadIdx.x < Co) bl[threadIdx.x] = bias[threadIdx.x];
    __syncthreads();

    int bid   = blockIdx.x;
    int local = bid % (NG*128);
    int b     = bid / (NG*128);
    int cb    = local & 3;            // 4 col-blocks of 128
    int rb    = (local >> 2) & 31;    // 32 row-blocks of 16
    int cg    = local >> 7;           // oc group
    int tid   = threadIdx.x;
    int lane  = tid & 31;
    int col   = cb*128 + lane*4;
    int row0  = rb*16  + (tid >> 5)*2;
    int co0   = cg*8;
    const float* inb = in + (size_t)b*Ci*HW;

    int  hcofs[4]; bool hok[4];
    #pragma unroll
    for (int dy=0;dy<4;dy++){
        int hh = row0 + dy - 1;
        int hc = hh < 0 ? 0 : (hh > HH-1 ? HH-1 : hh);
        hok[dy]   = (unsigned)hh < (unsigned)HH;
        hcofs[dy] = hc*WW;
    }

    float acc[8][2][4];
    #pragma unroll
    for (int j=0;j<8;j++){
        float bv = bl[co0+j];
        #pragma unroll
        for (int r=0;r<2;r++)
            #pragma unroll
            for (int p=0;p<4;p++) acc[j][r][p] = bv;
    }

    if constexpr (UNR == 4){
        #pragma unroll 4
        for (int ci=0; ci<Ci; ci++) CIBODY
    } else if constexpr (UNR == 2){
        #pragma unroll 2
        for (int ci=0; ci<Ci; ci++) CIBODY
    } else {
        #pragma unroll 1
        for (int ci=0; ci<Ci; ci++) CIBODY
    }

    float* ob = outp + (size_t)b*Co*HW;
    #pragma unroll
    for (int j=0;j<8;j++){
        #pragma unroll
        for (int r=0;r<2;r++){
            float4 o;
            o.x = LRELU ? lrelu_f(acc[j][r][0]) : acc[j][r][0];
            o.y = LRELU ? lrelu_f(acc[j][r][1]) : acc[j][r][1];
            o.z = LRELU ? lrelu_f(acc[j][r][2]) : acc[j][r][2];
            o.w = LRELU ? lrelu_f(acc[j][r][3]) : acc[j][r][3];
            *(float4*)(ob + (size_t)(co0+j)*HW + (size_t)(row0+r)*WW + col) = o;
        }
    }
}

// ---------------------------------------------------------------------------
// One scale's per-row step inside k_std3 (r8 structure; swz3 padding).
// ---------------------------------------------------------------------------
template<int WS>
__device__ __forceinline__ float scale_step(float2* __restrict__ svq,
                                            float* __restrict__ resv,
                                            const float* vs, const float* vq,
                                            float fws)
{
    constexpr int P   = WS/2;
    constexpr int OFF = 24 - P;
    constexpr float inv = 1.f/((float)WS*(float)WS);
    const int tid = threadIdx.x;
    const int ch  = tid >> 5;
    const int seg = tid & 31;

    __syncthreads();                        // svq/resv free of prior readers
    #pragma unroll
    for (int k=0;k<SEGC;k++){
        int j = k*32 + seg;
        svq[ch*SVW + swz(j)] = make_float2(vs[k], vq[k]);
    }
    __syncthreads();

    int base = OFF + seg*8;
    float S = 0.f, Q = 0.f;
    #pragma unroll
    for (int q=0;q<WS;q++){
        float2 t = svq[ch*SVW + swz(base+q)];
        S += t.x; Q += t.y;
    }
    float res[8];
    #pragma unroll
    for (int t8=0;t8<8;t8++){
        float m = S*inv, m2 = Q*inv;
        res[t8] = sqrtf(fmaxf(fmaf(-m, m, m2), 1e-6f));
        if (t8 < 7){
            float2 ta = svq[ch*SVW + swz(base+t8+WS)];
            float2 tb = svq[ch*SVW + swz(base+t8)];
            S += ta.x - tb.x; Q += ta.y - tb.y;
        }
    }
    #pragma unroll
    for (int t8=0;t8<8;t8++)
        resv[ch*RSW + swz(seg*8+t8)] = res[t8];
    __syncthreads();

    float a = 0.f;
    #pragma unroll
    for (int cc=0;cc<CF;cc++) a += resv[cc*RSW + swz(tid)];
    return fws * powf(a*0.125f, 0.8f);
}

// ---------------------------------------------------------------------------
// ALL-3-SCALES fused std-map kernel + final fused write + level-1 histogram.
// ---------------------------------------------------------------------------
__global__ __launch_bounds__(256) void k_std3(const float* __restrict__ f,
                                              float* __restrict__ fused,
                                              const float* __restrict__ fwv,
                                              const float* __restrict__ fbp,
                                              unsigned* __restrict__ hist8)
{
    __shared__ float2 svq[CF*SVW];
    __shared__ float  resv[CF*RSW];
    __shared__ unsigned lh8[256];
    lh8[threadIdx.x] = 0;   // visible by first scale_step's barrier

    int bid  = blockIdx.x;
    int band = bid & 31;
    int half = (bid >> 5) & 1;
    int b    = bid >> 6;
    int r0   = band*16;
    int c0   = half*256;
    int tid  = threadIdx.x;
    int ch   = tid >> 5;
    int seg  = tid & 31;
    const float* fp = f + (size_t)(b*CF + ch)*HW;

    int rc[SEGC];
    #pragma unroll
    for (int k=0;k<SEGC;k++){
        int gc = c0 - 24 + k*32 + seg;
        gc = gc < 0 ? -gc : (gc > WW-1 ? 2*WW-2 - gc : gc);
        rc[k] = gc;
    }

    float vs49[SEGC], vq49[SEGC], vs25[SEGC], vq25[SEGC], vs11[SEGC], vq11[SEGC];
    #pragma unroll
    for (int k=0;k<SEGC;k++){
        vs49[k]=0.f; vq49[k]=0.f; vs25[k]=0.f; vq25[k]=0.f; vs11[k]=0.f; vq11[k]=0.f;
    }
    #pragma unroll 1
    for (int dy=-24; dy<=24; dy++){
        const float* rp = fp + (size_t)reflect_i(r0+dy)*WW;
        bool in25 = (dy >= -12 && dy <= 12);
        bool in11 = (dy >= -5  && dy <= 5);
        #pragma unroll
        for (int k=0;k<SEGC;k++){
            float v = rp[rc[k]]; float v2 = v*v;
            vs49[k] += v; vq49[k] += v2;
            if (in25){ vs25[k] += v; vq25[k] += v2; }
            if (in11){ vs11[k] += v; vq11[k] += v2; }
        }
    }

    float fw0 = fwv[0], fw1 = fwv[1], fw2 = fwv[2];
    float fbv = fbp[0];

    for (int rr=0; rr<16; rr++){
        int r = r0 + rr;
        float val;
        val  = scale_step<11>(svq, resv, vs11, vq11, fw0);
        val += scale_step<25>(svq, resv, vs25, vq25, fw1);
        val += scale_step<49>(svq, resv, vs49, vq49, fw2);
        float F = fmaxf(val + fbv, 0.f);
        fused[((size_t)b*HH + r)*WW + c0 + tid] = F;
        atomicAdd(&lh8[__float_as_uint(F) >> 24], 1u);
        if (rr < 15){
            {   const float* ep = fp + (size_t)reflect_i(r+25)*WW;
                const float* lp = fp + (size_t)reflect_i(r-24)*WW;
                #pragma unroll
                for (int k=0;k<SEGC;k++){
                    float e = ep[rc[k]], l = lp[rc[k]];
                    vs49[k] += e - l;
                    vq49[k] = fmaf(e, e, vq49[k]); vq49[k] = fmaf(-l, l, vq49[k]);
                }
            }
            {   const float* ep = fp + (size_t)reflect_i(r+13)*WW;
                const float* lp = fp + (size_t)reflect_i(r-12)*WW;
                #pragma unroll
                for (int k=0;k<SEGC;k++){
                    float e = ep[rc[k]], l = lp[rc[k]];
                    vs25[k] += e - l;
                    vq25[k] = fmaf(e, e, vq25[k]); vq25[k] = fmaf(-l, l, vq25[k]);
                }
            }
            {   const float* ep = fp + (size_t)reflect_i(r+6)*WW;
                const float* lp = fp + (size_t)reflect_i(r-5)*WW;
                #pragma unroll
                for (int k=0;k<SEGC;k++){
                    float e = ep[rc[k]], l = lp[rc[k]];
                    vs11[k] += e - l;
                    vq11[k] = fmaf(e, e, vq11[k]); vq11[k] = fmaf(-l, l, vq11[k]);
                }
            }
        }
    }
    __syncthreads();
    if (lh8[tid]) atomicAdd(&hist8[tid], lh8[tid]);
}

// ---------------------------------------------------------------------------
// Quantile refinement (fused values are stored FINAL: >=0, bias applied).
// ---------------------------------------------------------------------------
__global__ void k_scan8(const unsigned* __restrict__ hist8,
                        int* __restrict__ cand8, int* __restrict__ rank8)
{
    if (threadIdx.x == 0){
        const unsigned RK[4] = {524287u, 524288u, 1572863u, 1572864u};
        unsigned cum = 0; int qi = 0;
        for (int b = 0; b < 256 && qi < 4; b++){
            unsigned cnt = hist8[b];
            while (qi < 4 && RK[qi] < cum + cnt){
                cand8[qi] = b; rank8[qi] = (int)(RK[qi] - cum); qi++;
            }
            cum += cnt;
        }
    }
}

__global__ void k_h8b(const float* __restrict__ fused,
                      const int* __restrict__ cand8, unsigned* __restrict__ hist8b)
{
    __shared__ unsigned lh[1024];
    for (int i = threadIdx.x; i < 1024; i += 256) lh[i] = 0;
    __syncthreads();
    int c0 = cand8[0], c1 = cand8[1], c2 = cand8[2], c3 = cand8[3];
    bool d1 = (c1 != c0);
    bool d2 = (c2 != c0) && (c2 != c1);
    bool d3 = (c3 != c0) && (c3 != c1) && (c3 != c2);
    int i = blockIdx.x*256 + threadIdx.x;
    int stride = gridDim.x*256;
    for (; i < NPIX; i += stride){
        unsigned u = __float_as_uint(fused[i]);
        int hi = (int)(u >> 24);
        unsigned mid = (u >> 16) & 0xffu;
        if (hi == c0)       atomicAdd(&lh[mid],       1u);
        if (d1 && hi == c1) atomicAdd(&lh[256u+mid],  1u);
        if (d2 && hi == c2) atomicAdd(&lh[512u+mid],  1u);
        if (d3 && hi == c3) atomicAdd(&lh[768u+mid],  1u);
    }
    __syncthreads();
    for (int i = threadIdx.x; i < 1024; i += 256)
        if (lh[i]) atomicAdd(&hist8b[i], lh[i]);
}

__global__ void k_scan8b(const unsigned* __restrict__ hist8b,
                         const int* __restrict__ cand8, const int* __restrict__ rank8,
                         int* __restrict__ cand16, int* __restrict__ rank16)
{
    int qi = threadIdx.x;
    if (qi < 4){
        int slot = qi;
        for (int j = 0; j < qi; j++) if (cand8[j] == cand8[qi]){ slot = j; break; }
        const unsigned* h = hist8b + slot*256;
        unsigned k = (unsigned)rank8[qi], cum = 0;
        for (int b = 0; b < 256; b++){
            unsigned cnt = h[b];
            if (cnt && k >= cum && k < cum + cnt){
                cand16[qi] = (cand8[qi] << 8) | b;
                rank16[qi] = (int)(k - cum);
            }
            cum += cnt;
        }
    }
}

__global__ void k_h16(const float* __restrict__ fused,
                      const int* __restrict__ cand16, unsigned* __restrict__ histlo)
{
    int c0 = cand16[0], c1 = cand16[1], c2 = cand16[2], c3 = cand16[3];
    bool d1 = (c1 != c0);
    bool d2 = (c2 != c0) && (c2 != c1);
    bool d3 = (c3 != c0) && (c3 != c1) && (c3 != c2);
    int i = blockIdx.x*256 + threadIdx.x;
    int stride = gridDim.x*256;
    for (; i < NPIX; i += stride){
        unsigned u = __float_as_uint(fused[i]);
        int hi = (int)(u >> 16);
        unsigned lo = u & 0xffffu;
        if (hi == c0)       atomicAdd(&histlo[lo],           1u);
        if (d1 && hi == c1) atomicAdd(&histlo[65536u + lo],  1u);
        if (d2 && hi == c2) atomicAdd(&histlo[131072u + lo], 1u);
        if (d3 && hi == c3) atomicAdd(&histlo[196608u + lo], 1u);
    }
}

// ---------------------------------------------------------------------------
// Level-3 scan: 4 PARALLEL blocks, uint4-vectorized chunk reads.
// ---------------------------------------------------------------------------
__global__ void k_scan16(const unsigned* __restrict__ histlo,
                         const int* __restrict__ cand16, const int* __restrict__ rank16,
                         float* __restrict__ ostat)
{
    int qi = blockIdx.x;
    int slot = qi;
    for (int j = 0; j < qi; j++) if (cand16[j] == cand16[qi]){ slot = j; break; }
    const uint4* hist4 = (const uint4*)(histlo + (size_t)slot*65536);
    __shared__ unsigned csum[256];
    __shared__ unsigned cbase[256];
    int t = threadIdx.x;
    unsigned s = 0;
    #pragma unroll 8
    for (int i = 0; i < 64; i++){
        uint4 v = hist4[t*64 + i];
        s += v.x + v.y + v.z + v.w;
    }
    csum[t] = s;
    __syncthreads();
    if (t == 0){ unsigned run = 0; for (int i = 0; i < 256; i++){ cbase[i] = run; run += csum[i]; } }
    __syncthreads();
    unsigned k = (unsigned)rank16[qi];
    unsigned cum = cbase[t];
    if (k >= cum && k < cum + csum[t]){         // only the owning thread rescans
        for (int i = 0; i < 64; i++){
            uint4 v = hist4[t*64 + i];
            unsigned a4[4] = {v.x, v.y, v.z, v.w};
            #pragma unroll
            for (int c = 0; c < 4; c++){
                if (a4[c] && k >= cum && k < cum + a4[c])
                    ostat[qi] = __uint_as_float(((unsigned)cand16[qi] << 16) | (unsigned)(t*256 + i*4 + c));
                cum += a4[c];
            }
        }
    }
}

// ---------------------------------------------------------------------------
// Global per-(b,c) std of x, ddof=1, double partial sums (deterministic).
// ---------------------------------------------------------------------------
__global__ void k_gstd_part(const float* __restrict__ x, double* __restrict__ part)
{
    int bid = blockIdx.x;
    int plane = bid >> 3, chunk = bid & 7;
    const float4* p4 = (const float4*)(x + (size_t)plane*HW + (size_t)chunk*32768);
    int t = threadIdx.x;
    double s=0.0, s2=0.0;
    for (int k=0;k<32;k++){
        float4 v = p4[k*256 + t];
        s  += (double)v.x + (double)v.y + (double)v.z + (double)v.w;
        s2 += (double)v.x*v.x + (double)v.y*v.y + (double)v.z*v.z + (double)v.w*v.w;
    }
    __shared__ double rs[256], rq[256];
    rs[t]=s; rq[t]=s2; __syncthreads();
    for (int off=128; off>0; off>>=1){
        if (t<off){ rs[t]+=rs[t+off]; rq[t]+=rq[t+off]; }
        __syncthreads();
    }
    if (t==0){ part[bid*2]=rs[0]; part[bid*2+1]=rq[0]; }
}

// ---------------------------------------------------------------------------
// Tiny epilogue: gstd final + thresholds (reads ostat[4]).
// ---------------------------------------------------------------------------
__global__ void k_fin2(const float* __restrict__ ostat,
                       const double* __restrict__ part, const float* __restrict__ cwin,
                       float* __restrict__ lov, float* __restrict__ hiv)
{
    int t = threadIdx.x;
    if (t < 32){
        double s=0.0, s2=0.0;
        for (int j=0;j<8;j++){ s += part[(t*8+j)*2]; s2 += part[(t*8+j)*2+1]; }
        const double N = 262144.0;
        double var = (s2 - s*s/N) / (N - 1.0);
        float g = (float)sqrt(var < 0.0 ? 0.0 : var);
        float q25 = ostat[0] + 0.75f*(ostat[1]-ostat[0]);
        float q75 = ostat[2] + 0.25f*(ostat[3]-ostat[2]);
        float iqr = q75 - q25;
        float lo_b = q25 - 0.5f*iqr, hi_b = q75 + 0.5f*iqr;
        int c = t & 3;
        float m = fmaxf(fmaxf(cwin[0],cwin[1]), fmaxf(cwin[2],cwin[3]));
        float e0 = expf(cwin[0]-m), e1 = expf(cwin[1]-m), e2 = expf(cwin[2]-m), e3 = expf(cwin[3]-m);
        float smc = expf(cwin[c]-m) / (e0+e1+e2+e3);
        float gf = fminf(fmaxf(g*5.f, 0.5f), 2.f);
        float cf = fminf(fmaxf(smc*g*2.f, 0.8f), 1.2f);
        lov[t] = lo_b*gf*cf;
        hiv[t] = hi_b*gf*cf;
    }
}

__global__ void k_mask(const float* __restrict__ fused_in,
                       const float* __restrict__ lov, const float* __restrict__ hiv,
                       float* __restrict__ outp)
{
    int i = blockIdx.x*256 + threadIdx.x;
    float F = fused_in[i];
    int b = i >> 18;
    float o = 0.f;
    #pragma unroll
    for (int c=0;c<4;c++){
        float lo = lov[b*4+c], hi = hiv[b*4+c];
        float n = (F - lo) / (hi - lo);
        n = fminf(fmaxf(n, 0.f), 1.f);
        o += 1.f/(1.f + expf(3.f - 6.f*n));
    }
    outp[i] = 0.25f * o;
}

// ---------------------------------------------------------------------------
extern "C" void kernel_launch(void* const* d_in, const int* in_sizes, int n_in,
                              void* d_out, int out_size, void* d_ws, size_t ws_size,
                              hipStream_t stream)
{
    const float* x  = (const float*)d_in[0];
    const float* w1 = (const float*)d_in[1];
    const float* b1 = (const float*)d_in[2];
    const float* w2 = (const float*)d_in[3];
    const float* b2 = (const float*)d_in[4];
    const float* w3 = (const float*)d_in[5];
    const float* b3 = (const float*)d_in[6];
    const float* fw = (const float*)d_in[7];
    const float* fb = (const float*)d_in[8];
    const float* cw = (const float*)d_in[9];
    float* out = (float*)d_out;
    char* ws = (char*)d_ws;

    size_t off = 0;
    auto take = [&](size_t bytes)->size_t{ size_t o = off; off += (bytes + 255) & ~(size_t)255; return o; };
    size_t o_h8     = take(256*4);                  // contiguous histogram
    size_t o_h8b    = take(1024*4);                 //  region: one memset
    size_t o_histlo = take((size_t)4*65536*4);
    size_t o_c8     = take(4*4);
    size_t o_r8     = take(4*4);
    size_t o_c16    = take(4*4);
    size_t o_r16    = take(4*4);
    size_t o_os     = take(4*4);
    size_t o_part   = take(512*8);
    size_t o_lo     = take(32*4);
    size_t o_hi     = take(32*4);
    // R1 (128 MiB): f2 full-batch during convs (dead after conv3).
    size_t o_R1     = take((size_t)NB*C3*HW*4);
    // R2 (64 MiB): f1 chunk during conv1/2, then fbuf (conv3 out, live thru std3).
    size_t o_R2     = take((size_t)NBC*C2*HW*4);

    float*    f2buf  = (float*)(ws + o_R1);
    float*    f1     = (float*)(ws + o_R2);
    float*    fbuf   = (float*)(ws + o_R2);
    unsigned* hist8  = (unsigned*)(ws + o_h8);
    unsigned* hist8b = (unsigned*)(ws + o_h8b);
    unsigned* histlo = (unsigned*)(ws + o_histlo);
    int*      c8     = (int*)(ws + o_c8);
    int*      r8     = (int*)(ws + o_r8);
    int*      c16    = (int*)(ws + o_c16);
    int*      r16    = (int*)(ws + o_r16);
    float*    osv    = (float*)(ws + o_os);
    double*   part   = (double*)(ws + o_part);
    float*    lov    = (float*)(ws + o_lo);
    float*    hiv    = (float*)(ws + o_hi);
    size_t hist_bytes = (o_histlo + (size_t)4*65536*4) - o_h8;

    // --- conv1+conv2 chunked (f2 full-batch; conv2 unroll-4), conv3 full-batch ---
    for (int ck = 0; ck < NB/NBC; ck++){
        const float* xb = x + (size_t)ck*NBC*CIN*HW;
        k_conv8<CIN,C2,true ,2><<<NBC*512,256,0,stream>>>(xb, w1, b1, f1);
        k_conv8<C2, C3,true ,4><<<NBC*256,256,0,stream>>>(f1, w2, b2,
                                                        f2buf + (size_t)ck*NBC*C3*HW);
    }
    k_conv8<C3, CF, false,1><<<NB*128,256,0,stream>>>(f2buf, w3, b3, fbuf);

    // --- global stds (independent of conv chain) ---
    k_gstd_part<<<256,256,0,stream>>>(x, part);

    // --- std maps + final fused write + level-1 histogram (fused) ---
    hipMemsetAsync(hist8, 0, hist_bytes, stream);
    k_std3<<<NB*2*32,256,0,stream>>>(fbuf, out, fw, fb, hist8);

    // --- quantile refinement (scan16: 4 parallel blocks, uint4 reads) ---
    k_scan8 <<<1,64,0,stream>>>(hist8, c8, r8);
    k_h8b   <<<2048,256,0,stream>>>(out, c8, hist8b);
    k_scan8b<<<1,64,0,stream>>>(hist8b, c8, r8, c16, r16);
    k_h16   <<<2048,256,0,stream>>>(out, c16, histlo);
    k_scan16<<<4,256,0,stream>>>(histlo, c16, r16, osv);
    k_fin2  <<<1,64,0,stream>>>(osv, part, cw, lov, hiv);

    // --- mask (in-place on d_out) ---
    k_mask<<<NPIX/256,256,0,stream>>>(out, lov, hiv, out);
}

// Round 15
// 764.009 us; speedup vs baseline: 1.2968x; 1.2968x over previous
//
#include <hip/hip_runtime.h>
#include <cmath>

#define HH 512
#define WW 512
#define NB 8
#define CIN 4
#define C2 32
#define C3 16
#define CF 8
#define HW (HH*WW)      /* 262144 */
#define NPIX (NB*HW)    /* 2097152 */
#define NBC 2           /* batches per conv chunk (ws_size < 267 MB) */

#define SEGC 10                          /* staged cols per thread (320/32) */
#define SW   320                         /* staged cols (304 used, P=24 halo) */
#define SVW  ((SW + (SW>>3) + 4) | 1)    /* float2 LDS row stride (swz3 pad) */
#define RSW  (256 + 32 + 4)

__device__ __forceinline__ float lrelu_f(float v){ return v < 0.f ? 0.2f*v : v; }
__device__ __forceinline__ int reflect_i(int i){ int r = i < 0 ? -i : i; return r >= HH ? 2*HH - 2 - r : r; }
__device__ __forceinline__ int swz(int j){ return j + (j >> 3); }

// ---------------------------------------------------------------------------
// Conv 3x3 (zero pad=1, OIHW). Thread = 2 rows x 4 cols x 8 oc. Weights
// transposed in LDS [g][ci][tap*8+oc]. UNR=2 is the empirical optimum
// (r13: 770us). unroll-4 (r14), manual PF (r11), SGPR weights (r5), and
// conv1+2 LDS fusion (r4) all regressed: the kernel lives in a narrow
// VGPR sweet spot (~112-160); mandated extra live state -> spills.
// ---------------------------------------------------------------------------
#define CIBODY \
    { \
        const float* inc = inb + (size_t)ci*HW; \
        float v[4][6]; \
        _Pragma("unroll") \
        for (int dy=0;dy<4;dy++){ \
            const float* rowp = inc + hcofs[dy]; \
            float4 mq = *(const float4*)(rowp + col); \
            float v0 = (col > 0)    ? rowp[col-1] : 0.f; \
            float v5 = (col+4 < WW) ? rowp[col+4] : 0.f; \
            if (!hok[dy]){ mq.x=0.f; mq.y=0.f; mq.z=0.f; mq.w=0.f; v0=0.f; v5=0.f; } \
            v[dy][0]=v0; v[dy][1]=mq.x; v[dy][2]=mq.y; \
            v[dy][3]=mq.z; v[dy][4]=mq.w; v[dy][5]=v5; \
        } \
        const float* wp = &wl[(cg*Ci + ci)*72]; \
        _Pragma("unroll") \
        for (int t=0;t<9;t++){ \
            int dy = t/3, dx = t - 3*(t/3); \
            float w8[8]; \
            _Pragma("unroll") \
            for (int o=0;o<8;o++) w8[o] = wp[t*8 + o]; \
            _Pragma("unroll") \
            for (int o=0;o<8;o++) \
                _Pragma("unroll") \
                for (int r=0;r<2;r++) \
                    _Pragma("unroll") \
                    for (int p=0;p<4;p++) \
                        acc[o][r][p] = fmaf(v[dy+r][dx+p], w8[o], acc[o][r][p]); \
        } \
    }

template<int Ci, int Co, bool LRELU, int UNR>
__global__ __launch_bounds__(256) void k_conv8(const float* __restrict__ in,
                                               const float* __restrict__ wgt,
                                               const float* __restrict__ bias,
                                               float* __restrict__ outp)
{
    constexpr int NG = Co/8;
    __shared__ float wl[NG*Ci*72];   // [g][ci][tap*8+ocl]
    __shared__ float bl[Co];
    for (int i = threadIdx.x; i < Co*Ci*9; i += 256){
        int g  = i / (Ci*72);
        int r  = i - g*(Ci*72);
        int ci = r / 72;
        int q  = r - ci*72;
        int tap = q >> 3, ocl = q & 7;
        wl[i] = wgt[((g*8 + ocl)*Ci + ci)*9 + tap];
    }
    if (threadIdx.x < Co) bl[threadIdx.x] = bias[threadIdx.x];
    __syncthreads();

    int bid   = blockIdx.x;
    int local = bid % (NG*128);
    int b     = bid / (NG*128);
    int cb    = local & 3;            // 4 col-blocks of 128
    int rb    = (local >> 2) & 31;    // 32 row-blocks of 16
    int cg    = local >> 7;           // oc group
    int tid   = threadIdx.x;
    int lane  = tid & 31;
    int col   = cb*128 + lane*4;
    int row0  = rb*16  + (tid >> 5)*2;
    int co0   = cg*8;
    const float* inb = in + (size_t)b*Ci*HW;

    int  hcofs[4]; bool hok[4];
    #pragma unroll
    for (int dy=0;dy<4;dy++){
        int hh = row0 + dy - 1;
        int hc = hh < 0 ? 0 : (hh > HH-1 ? HH-1 : hh);
        hok[dy]   = (unsigned)hh < (unsigned)HH;
        hcofs[dy] = hc*WW;
    }

    float acc[8][2][4];
    #pragma unroll
    for (int j=0;j<8;j++){
        float bv = bl[co0+j];
        #pragma unroll
        for (int r=0;r<2;r++)
            #pragma unroll
            for (int p=0;p<4;p++) acc[j][r][p] = bv;
    }

    if constexpr (UNR == 2){
        #pragma unroll 2
        for (int ci=0; ci<Ci; ci++) CIBODY
    } else {
        #pragma unroll 1
        for (int ci=0; ci<Ci; ci++) CIBODY
    }

    float* ob = outp + (size_t)b*Co*HW;
    #pragma unroll
    for (int j=0;j<8;j++){
        #pragma unroll
        for (int r=0;r<2;r++){
            float4 o;
            o.x = LRELU ? lrelu_f(acc[j][r][0]) : acc[j][r][0];
            o.y = LRELU ? lrelu_f(acc[j][r][1]) : acc[j][r][1];
            o.z = LRELU ? lrelu_f(acc[j][r][2]) : acc[j][r][2];
            o.w = LRELU ? lrelu_f(acc[j][r][3]) : acc[j][r][3];
            *(float4*)(ob + (size_t)(co0+j)*HW + (size_t)(row0+r)*WW + col) = o;
        }
    }
}

// ---------------------------------------------------------------------------
// One scale's per-row step inside k_std3 (r8 structure; swz3 padding).
// ---------------------------------------------------------------------------
template<int WS>
__device__ __forceinline__ float scale_step(float2* __restrict__ svq,
                                            float* __restrict__ resv,
                                            const float* vs, const float* vq,
                                            float fws)
{
    constexpr int P   = WS/2;
    constexpr int OFF = 24 - P;
    constexpr float inv = 1.f/((float)WS*(float)WS);
    const int tid = threadIdx.x;
    const int ch  = tid >> 5;
    const int seg = tid & 31;

    __syncthreads();                        // svq/resv free of prior readers
    #pragma unroll
    for (int k=0;k<SEGC;k++){
        int j = k*32 + seg;
        svq[ch*SVW + swz(j)] = make_float2(vs[k], vq[k]);
    }
    __syncthreads();

    int base = OFF + seg*8;
    float S = 0.f, Q = 0.f;
    #pragma unroll
    for (int q=0;q<WS;q++){
        float2 t = svq[ch*SVW + swz(base+q)];
        S += t.x; Q += t.y;
    }
    float res[8];
    #pragma unroll
    for (int t8=0;t8<8;t8++){
        float m = S*inv, m2 = Q*inv;
        res[t8] = sqrtf(fmaxf(fmaf(-m, m, m2), 1e-6f));
        if (t8 < 7){
            float2 ta = svq[ch*SVW + swz(base+t8+WS)];
            float2 tb = svq[ch*SVW + swz(base+t8)];
            S += ta.x - tb.x; Q += ta.y - tb.y;
        }
    }
    #pragma unroll
    for (int t8=0;t8<8;t8++)
        resv[ch*RSW + swz(seg*8+t8)] = res[t8];
    __syncthreads();

    float a = 0.f;
    #pragma unroll
    for (int cc=0;cc<CF;cc++) a += resv[cc*RSW + swz(tid)];
    return fws * powf(a*0.125f, 0.8f);
}

// ---------------------------------------------------------------------------
// ALL-3-SCALES fused std-map kernel + final fused write + level-1 histogram.
// ---------------------------------------------------------------------------
__global__ __launch_bounds__(256) void k_std3(const float* __restrict__ f,
                                              float* __restrict__ fused,
                                              const float* __restrict__ fwv,
                                              const float* __restrict__ fbp,
                                              unsigned* __restrict__ hist8)
{
    __shared__ float2 svq[CF*SVW];
    __shared__ float  resv[CF*RSW];
    __shared__ unsigned lh8[256];
    lh8[threadIdx.x] = 0;   // visible by first scale_step's barrier

    int bid  = blockIdx.x;
    int band = bid & 31;
    int half = (bid >> 5) & 1;
    int b    = bid >> 6;
    int r0   = band*16;
    int c0   = half*256;
    int tid  = threadIdx.x;
    int ch   = tid >> 5;
    int seg  = tid & 31;
    const float* fp = f + (size_t)(b*CF + ch)*HW;

    int rc[SEGC];
    #pragma unroll
    for (int k=0;k<SEGC;k++){
        int gc = c0 - 24 + k*32 + seg;
        gc = gc < 0 ? -gc : (gc > WW-1 ? 2*WW-2 - gc : gc);
        rc[k] = gc;
    }

    float vs49[SEGC], vq49[SEGC], vs25[SEGC], vq25[SEGC], vs11[SEGC], vq11[SEGC];
    #pragma unroll
    for (int k=0;k<SEGC;k++){
        vs49[k]=0.f; vq49[k]=0.f; vs25[k]=0.f; vq25[k]=0.f; vs11[k]=0.f; vq11[k]=0.f;
    }
    #pragma unroll 1
    for (int dy=-24; dy<=24; dy++){
        const float* rp = fp + (size_t)reflect_i(r0+dy)*WW;
        bool in25 = (dy >= -12 && dy <= 12);
        bool in11 = (dy >= -5  && dy <= 5);
        #pragma unroll
        for (int k=0;k<SEGC;k++){
            float v = rp[rc[k]]; float v2 = v*v;
            vs49[k] += v; vq49[k] += v2;
            if (in25){ vs25[k] += v; vq25[k] += v2; }
            if (in11){ vs11[k] += v; vq11[k] += v2; }
        }
    }

    float fw0 = fwv[0], fw1 = fwv[1], fw2 = fwv[2];
    float fbv = fbp[0];

    for (int rr=0; rr<16; rr++){
        int r = r0 + rr;
        float val;
        val  = scale_step<11>(svq, resv, vs11, vq11, fw0);
        val += scale_step<25>(svq, resv, vs25, vq25, fw1);
        val += scale_step<49>(svq, resv, vs49, vq49, fw2);
        float F = fmaxf(val + fbv, 0.f);
        fused[((size_t)b*HH + r)*WW + c0 + tid] = F;
        atomicAdd(&lh8[__float_as_uint(F) >> 24], 1u);
        if (rr < 15){
            {   const float* ep = fp + (size_t)reflect_i(r+25)*WW;
                const float* lp = fp + (size_t)reflect_i(r-24)*WW;
                #pragma unroll
                for (int k=0;k<SEGC;k++){
                    float e = ep[rc[k]], l = lp[rc[k]];
                    vs49[k] += e - l;
                    vq49[k] = fmaf(e, e, vq49[k]); vq49[k] = fmaf(-l, l, vq49[k]);
                }
            }
            {   const float* ep = fp + (size_t)reflect_i(r+13)*WW;
                const float* lp = fp + (size_t)reflect_i(r-12)*WW;
                #pragma unroll
                for (int k=0;k<SEGC;k++){
                    float e = ep[rc[k]], l = lp[rc[k]];
                    vs25[k] += e - l;
                    vq25[k] = fmaf(e, e, vq25[k]); vq25[k] = fmaf(-l, l, vq25[k]);
                }
            }
            {   const float* ep = fp + (size_t)reflect_i(r+6)*WW;
                const float* lp = fp + (size_t)reflect_i(r-5)*WW;
                #pragma unroll
                for (int k=0;k<SEGC;k++){
                    float e = ep[rc[k]], l = lp[rc[k]];
                    vs11[k] += e - l;
                    vq11[k] = fmaf(e, e, vq11[k]); vq11[k] = fmaf(-l, l, vq11[k]);
                }
            }
        }
    }
    __syncthreads();
    if (lh8[tid]) atomicAdd(&hist8[tid], lh8[tid]);
}

// ---------------------------------------------------------------------------
// Quantile refinement (fused values are stored FINAL: >=0, bias applied).
// ---------------------------------------------------------------------------
__global__ void k_scan8(const unsigned* __restrict__ hist8,
                        int* __restrict__ cand8, int* __restrict__ rank8)
{
    if (threadIdx.x == 0){
        const unsigned RK[4] = {524287u, 524288u, 1572863u, 1572864u};
        unsigned cum = 0; int qi = 0;
        for (int b = 0; b < 256 && qi < 4; b++){
            unsigned cnt = hist8[b];
            while (qi < 4 && RK[qi] < cum + cnt){
                cand8[qi] = b; rank8[qi] = (int)(RK[qi] - cum); qi++;
            }
            cum += cnt;
        }
    }
}

__global__ void k_h8b(const float* __restrict__ fused,
                      const int* __restrict__ cand8, unsigned* __restrict__ hist8b)
{
    __shared__ unsigned lh[1024];
    for (int i = threadIdx.x; i < 1024; i += 256) lh[i] = 0;
    __syncthreads();
    int c0 = cand8[0], c1 = cand8[1], c2 = cand8[2], c3 = cand8[3];
    bool d1 = (c1 != c0);
    bool d2 = (c2 != c0) && (c2 != c1);
    bool d3 = (c3 != c0) && (c3 != c1) && (c3 != c2);
    int i = blockIdx.x*256 + threadIdx.x;
    int stride = gridDim.x*256;
    for (; i < NPIX; i += stride){
        unsigned u = __float_as_uint(fused[i]);
        int hi = (int)(u >> 24);
        unsigned mid = (u >> 16) & 0xffu;
        if (hi == c0)       atomicAdd(&lh[mid],       1u);
        if (d1 && hi == c1) atomicAdd(&lh[256u+mid],  1u);
        if (d2 && hi == c2) atomicAdd(&lh[512u+mid],  1u);
        if (d3 && hi == c3) atomicAdd(&lh[768u+mid],  1u);
    }
    __syncthreads();
    for (int i = threadIdx.x; i < 1024; i += 256)
        if (lh[i]) atomicAdd(&hist8b[i], lh[i]);
}

__global__ void k_scan8b(const unsigned* __restrict__ hist8b,
                         const int* __restrict__ cand8, const int* __restrict__ rank8,
                         int* __restrict__ cand16, int* __restrict__ rank16)
{
    int qi = threadIdx.x;
    if (qi < 4){
        int slot = qi;
        for (int j = 0; j < qi; j++) if (cand8[j] == cand8[qi]){ slot = j; break; }
        const unsigned* h = hist8b + slot*256;
        unsigned k = (unsigned)rank8[qi], cum = 0;
        for (int b = 0; b < 256; b++){
            unsigned cnt = h[b];
            if (cnt && k >= cum && k < cum + cnt){
                cand16[qi] = (cand8[qi] << 8) | b;
                rank16[qi] = (int)(k - cum);
            }
            cum += cnt;
        }
    }
}

__global__ void k_h16(const float* __restrict__ fused,
                      const int* __restrict__ cand16, unsigned* __restrict__ histlo)
{
    int c0 = cand16[0], c1 = cand16[1], c2 = cand16[2], c3 = cand16[3];
    bool d1 = (c1 != c0);
    bool d2 = (c2 != c0) && (c2 != c1);
    bool d3 = (c3 != c0) && (c3 != c1) && (c3 != c2);
    int i = blockIdx.x*256 + threadIdx.x;
    int stride = gridDim.x*256;
    for (; i < NPIX; i += stride){
        unsigned u = __float_as_uint(fused[i]);
        int hi = (int)(u >> 16);
        unsigned lo = u & 0xffffu;
        if (hi == c0)       atomicAdd(&histlo[lo],           1u);
        if (d1 && hi == c1) atomicAdd(&histlo[65536u + lo],  1u);
        if (d2 && hi == c2) atomicAdd(&histlo[131072u + lo], 1u);
        if (d3 && hi == c3) atomicAdd(&histlo[196608u + lo], 1u);
    }
}

// ---------------------------------------------------------------------------
// Level-3 scan: 4 PARALLEL blocks, uint4-vectorized chunk reads.
// ---------------------------------------------------------------------------
__global__ void k_scan16(const unsigned* __restrict__ histlo,
                         const int* __restrict__ cand16, const int* __restrict__ rank16,
                         float* __restrict__ ostat)
{
    int qi = blockIdx.x;
    int slot = qi;
    for (int j = 0; j < qi; j++) if (cand16[j] == cand16[qi]){ slot = j; break; }
    const uint4* hist4 = (const uint4*)(histlo + (size_t)slot*65536);
    __shared__ unsigned csum[256];
    __shared__ unsigned cbase[256];
    int t = threadIdx.x;
    unsigned s = 0;
    #pragma unroll 8
    for (int i = 0; i < 64; i++){
        uint4 v = hist4[t*64 + i];
        s += v.x + v.y + v.z + v.w;
    }
    csum[t] = s;
    __syncthreads();
    if (t == 0){ unsigned run = 0; for (int i = 0; i < 256; i++){ cbase[i] = run; run += csum[i]; } }
    __syncthreads();
    unsigned k = (unsigned)rank16[qi];
    unsigned cum = cbase[t];
    if (k >= cum && k < cum + csum[t]){         // only the owning thread rescans
        for (int i = 0; i < 64; i++){
            uint4 v = hist4[t*64 + i];
            unsigned a4[4] = {v.x, v.y, v.z, v.w};
            #pragma unroll
            for (int c = 0; c < 4; c++){
                if (a4[c] && k >= cum && k < cum + a4[c])
                    ostat[qi] = __uint_as_float(((unsigned)cand16[qi] << 16) | (unsigned)(t*256 + i*4 + c));
                cum += a4[c];
            }
        }
    }
}

// ---------------------------------------------------------------------------
// Global per-(b,c) std of x, ddof=1, double partial sums (deterministic).
// ---------------------------------------------------------------------------
__global__ void k_gstd_part(const float* __restrict__ x, double* __restrict__ part)
{
    int bid = blockIdx.x;
    int plane = bid >> 3, chunk = bid & 7;
    const float4* p4 = (const float4*)(x + (size_t)plane*HW + (size_t)chunk*32768);
    int t = threadIdx.x;
    double s=0.0, s2=0.0;
    for (int k=0;k<32;k++){
        float4 v = p4[k*256 + t];
        s  += (double)v.x + (double)v.y + (double)v.z + (double)v.w;
        s2 += (double)v.x*v.x + (double)v.y*v.y + (double)v.z*v.z + (double)v.w*v.w;
    }
    __shared__ double rs[256], rq[256];
    rs[t]=s; rq[t]=s2; __syncthreads();
    for (int off=128; off>0; off>>=1){
        if (t<off){ rs[t]+=rs[t+off]; rq[t]+=rq[t+off]; }
        __syncthreads();
    }
    if (t==0){ part[bid*2]=rs[0]; part[bid*2+1]=rq[0]; }
}

// ---------------------------------------------------------------------------
// Tiny epilogue: gstd final + thresholds (reads ostat[4]).
// ---------------------------------------------------------------------------
__global__ void k_fin2(const float* __restrict__ ostat,
                       const double* __restrict__ part, const float* __restrict__ cwin,
                       float* __restrict__ lov, float* __restrict__ hiv)
{
    int t = threadIdx.x;
    if (t < 32){
        double s=0.0, s2=0.0;
        for (int j=0;j<8;j++){ s += part[(t*8+j)*2]; s2 += part[(t*8+j)*2+1]; }
        const double N = 262144.0;
        double var = (s2 - s*s/N) / (N - 1.0);
        float g = (float)sqrt(var < 0.0 ? 0.0 : var);
        float q25 = ostat[0] + 0.75f*(ostat[1]-ostat[0]);
        float q75 = ostat[2] + 0.25f*(ostat[3]-ostat[2]);
        float iqr = q75 - q25;
        float lo_b = q25 - 0.5f*iqr, hi_b = q75 + 0.5f*iqr;
        int c = t & 3;
        float m = fmaxf(fmaxf(cwin[0],cwin[1]), fmaxf(cwin[2],cwin[3]));
        float e0 = expf(cwin[0]-m), e1 = expf(cwin[1]-m), e2 = expf(cwin[2]-m), e3 = expf(cwin[3]-m);
        float smc = expf(cwin[c]-m) / (e0+e1+e2+e3);
        float gf = fminf(fmaxf(g*5.f, 0.5f), 2.f);
        float cf = fminf(fmaxf(smc*g*2.f, 0.8f), 1.2f);
        lov[t] = lo_b*gf*cf;
        hiv[t] = hi_b*gf*cf;
    }
}

__global__ void k_mask(const float* __restrict__ fused_in,
                       const float* __restrict__ lov, const float* __restrict__ hiv,
                       float* __restrict__ outp)
{
    int i = blockIdx.x*256 + threadIdx.x;
    float F = fused_in[i];
    int b = i >> 18;
    float o = 0.f;
    #pragma unroll
    for (int c=0;c<4;c++){
        float lo = lov[b*4+c], hi = hiv[b*4+c];
        float n = (F - lo) / (hi - lo);
        n = fminf(fmaxf(n, 0.f), 1.f);
        o += 1.f/(1.f + expf(3.f - 6.f*n));
    }
    outp[i] = 0.25f * o;
}

// ---------------------------------------------------------------------------
extern "C" void kernel_launch(void* const* d_in, const int* in_sizes, int n_in,
                              void* d_out, int out_size, void* d_ws, size_t ws_size,
                              hipStream_t stream)
{
    const float* x  = (const float*)d_in[0];
    const float* w1 = (const float*)d_in[1];
    const float* b1 = (const float*)d_in[2];
    const float* w2 = (const float*)d_in[3];
    const float* b2 = (const float*)d_in[4];
    const float* w3 = (const float*)d_in[5];
    const float* b3 = (const float*)d_in[6];
    const float* fw = (const float*)d_in[7];
    const float* fb = (const float*)d_in[8];
    const float* cw = (const float*)d_in[9];
    float* out = (float*)d_out;
    char* ws = (char*)d_ws;

    size_t off = 0;
    auto take = [&](size_t bytes)->size_t{ size_t o = off; off += (bytes + 255) & ~(size_t)255; return o; };
    size_t o_h8     = take(256*4);                  // contiguous histogram
    size_t o_h8b    = take(1024*4);                 //  region: one memset
    size_t o_histlo = take((size_t)4*65536*4);
    size_t o_c8     = take(4*4);
    size_t o_r8     = take(4*4);
    size_t o_c16    = take(4*4);
    size_t o_r16    = take(4*4);
    size_t o_os     = take(4*4);
    size_t o_part   = take(512*8);
    size_t o_lo     = take(32*4);
    size_t o_hi     = take(32*4);
    // R1 (128 MiB): f2 full-batch during convs (dead after conv3).
    size_t o_R1     = take((size_t)NB*C3*HW*4);
    // R2 (64 MiB): f1 chunk during conv1/2, then fbuf (conv3 out, live thru std3).
    size_t o_R2     = take((size_t)NBC*C2*HW*4);

    float*    f2buf  = (float*)(ws + o_R1);
    float*    f1     = (float*)(ws + o_R2);
    float*    fbuf   = (float*)(ws + o_R2);
    unsigned* hist8  = (unsigned*)(ws + o_h8);
    unsigned* hist8b = (unsigned*)(ws + o_h8b);
    unsigned* histlo = (unsigned*)(ws + o_histlo);
    int*      c8     = (int*)(ws + o_c8);
    int*      r8     = (int*)(ws + o_r8);
    int*      c16    = (int*)(ws + o_c16);
    int*      r16    = (int*)(ws + o_r16);
    float*    osv    = (float*)(ws + o_os);
    double*   part   = (double*)(ws + o_part);
    float*    lov    = (float*)(ws + o_lo);
    float*    hiv    = (float*)(ws + o_hi);
    size_t hist_bytes = (o_histlo + (size_t)4*65536*4) - o_h8;

    // --- conv1+conv2 chunked (f2 full-batch, unroll-2), conv3 full-batch ---
    for (int ck = 0; ck < NB/NBC; ck++){
        const float* xb = x + (size_t)ck*NBC*CIN*HW;
        k_conv8<CIN,C2,true ,2><<<NBC*512,256,0,stream>>>(xb, w1, b1, f1);
        k_conv8<C2, C3,true ,2><<<NBC*256,256,0,stream>>>(f1, w2, b2,
                                                        f2buf + (size_t)ck*NBC*C3*HW);
    }
    k_conv8<C3, CF, false,1><<<NB*128,256,0,stream>>>(f2buf, w3, b3, fbuf);

    // --- global stds (independent of conv chain) ---
    k_gstd_part<<<256,256,0,stream>>>(x, part);

    // --- std maps + final fused write + level-1 histogram (fused) ---
    hipMemsetAsync(hist8, 0, hist_bytes, stream);
    k_std3<<<NB*2*32,256,0,stream>>>(fbuf, out, fw, fb, hist8);

    // --- quantile refinement (scan16: 4 parallel blocks, uint4 reads) ---
    k_scan8 <<<1,64,0,stream>>>(hist8, c8, r8);
    k_h8b   <<<2048,256,0,stream>>>(out, c8, hist8b);
    k_scan8b<<<1,64,0,stream>>>(hist8b, c8, r8, c16, r16);
    k_h16   <<<2048,256,0,stream>>>(out, c16, histlo);
    k_scan16<<<4,256,0,stream>>>(histlo, c16, r16, osv);
    k_fin2  <<<1,64,0,stream>>>(osv, part, cw, lov, hiv);

    // --- mask (in-place on d_out) ---
    k_mask<<<NPIX/256,256,0,stream>>>(out, lov, hiv, out);
}